// Round 15
// baseline (26.527 us; speedup 1.0000x reference)
//
#include <hip/hip_runtime.h>
#include <hip/hip_bf16.h>

typedef float f4 __attribute__((ext_vector_type(4)));
typedef float f32x4 __attribute__((ext_vector_type(4)));
typedef short s16x8 __attribute__((ext_vector_type(8)));

// R14 + 2-group sequential processing: block = 4 waves, TWO 64-token
// groups. bfrag (wave's bf16 weight k-quarter, 32 VGPR) loaded once,
// covers 64 MFMAs; per-block fixed costs halve (256 blocks). Group 1's
// step-0 A-loads are hoisted into the dead ring slot BEFORE group 0's
// epilogue, so their latency hides under the barrier+softmax.
// clds rows padded to 17 floats: epilogue's stride-16 reads were a
// 32-way bank conflict, stride-17 is conflict-free.

#define TPB 128  // tokens per block (2 groups of 64)

__device__ __forceinline__ s16x8 pack8(f4 a, f4 b) {
  union { s16x8 v; __hip_bfloat162 h[4]; } u;
  u.h[0] = __float22bfloat162_rn({a.x, a.y});
  u.h[1] = __float22bfloat162_rn({a.z, a.w});
  u.h[2] = __float22bfloat162_rn({b.x, b.y});
  u.h[3] = __float22bfloat162_rn({b.z, b.w});
  return u.v;
}

__global__ __launch_bounds__(256)
void moa_mfma5(const float* __restrict__ tok,
               const float* __restrict__ Wq,
               const float* __restrict__ Wk,
               const float* __restrict__ Wv,
               float* __restrict__ out) {
  __shared__ float clds[4 * 64 * 17];             // 17.4 KB, reused per group
  const int tid  = threadIdx.x;
  const int wv   = tid >> 6;
  const int lane = tid & 63;
  const int n    = lane & 15;                     // A: token row / B: expert col
  const int kg   = lane >> 4;                     // k-group of 8
  const int kq   = wv * 256;                      // wave's k-quarter

  // ---- B-frags: this wave's weight quarter, bf16 (loaded ONCE) ----
  const float* wrow = (n < 3) ? (Wq + n * 1024)
                    : (n < 6) ? (Wk + (n - 3) * 1024)
                    : (Wv + ((n < 9) ? (n - 6) : 0) * 1024);   // cols 9..15 unused
  s16x8 bfrag[8];
#pragma unroll
  for (int s = 0; s < 8; ++s) {
    const float* p = wrow + kq + s * 32 + kg * 8;
    bfrag[s] = pack8(*(const f4*)p, *(const f4*)(p + 4));
  }

  const int T0 = blockIdx.x * TPB;
  const float* ap = tok + (size_t)(T0 + n) * 1024 + kq + kg * 8;

  f4 A[2][4][2];
#pragma unroll
  for (int t = 0; t < 4; ++t) {                   // group 0, step 0
    A[0][t][0] = *(const f4*)(ap + t * 16384);
    A[0][t][1] = *(const f4*)(ap + t * 16384 + 4);
  }

#pragma unroll
  for (int g = 0; g < 2; ++g) {
    const float* gp = ap + g * 65536;             // +64 rows

    f32x4 acc[4];
#pragma unroll
    for (int t = 0; t < 4; ++t) acc[t] = (f32x4){0.f, 0.f, 0.f, 0.f};

#pragma unroll
    for (int s = 0; s < 8; ++s) {
      const int cs = s & 1, ns = cs ^ 1;          // compile-time after unroll
      if (s < 7) {
#pragma unroll
        for (int t = 0; t < 4; ++t) {
          A[ns][t][0] = *(const f4*)(gp + t * 16384 + (s + 1) * 32);
          A[ns][t][1] = *(const f4*)(gp + t * 16384 + (s + 1) * 32 + 4);
        }
      }
#pragma unroll
      for (int t = 0; t < 4; ++t) {
        s16x8 a = pack8(A[cs][t][0], A[cs][t][1]);
        acc[t] = __builtin_amdgcn_mfma_f32_16x16x32_bf16(a, bfrag[s], acc[t], 0, 0, 0);
      }
    }

    // ---- hoist next group's step-0 loads into the dead slot A[0] ----
    if (g == 0) {
#pragma unroll
      for (int t = 0; t < 4; ++t) {
        A[0][t][0] = *(const f4*)(gp + 65536 + t * 16384);
        A[0][t][1] = *(const f4*)(gp + 65536 + t * 16384 + 4);
      }
    }

    // ---- combine 4 k-quarter partials via LDS (rows padded to 17) ----
    if (g == 1) __syncthreads();                  // group-0 readers done
#pragma unroll
    for (int t = 0; t < 4; ++t)
#pragma unroll
      for (int i = 0; i < 4; ++i) {
        const int row = t * 16 + kg * 4 + i;      // token-in-group (R6 layout)
        clds[wv * 1088 + row * 17 + n] = acc[t][i];
      }
    __syncthreads();

    // ---- 64 parallel softmaxes ----
    if (tid < 64) {
      float r[9];
#pragma unroll
      for (int j = 0; j < 9; ++j)
        r[j] = (clds[tid * 17 + j] + clds[1088 + tid * 17 + j]) +
               (clds[2176 + tid * 17 + j] + clds[3264 + tid * 17 + j]);
      float lg[3];
#pragma unroll
      for (int e = 0; e < 3; ++e) {
        float e0 = __expf(r[e] * r[3]);
        float e1 = __expf(r[e] * r[4]);
        float e2 = __expf(r[e] * r[5]);
        float den = (e0 + e1) + e2;
        float num = e0 * r[6] + e1 * r[7] + e2 * r[8];
        lg[e] = num * __builtin_amdgcn_rcpf(den);
      }
      float u0 = __expf(lg[0]);
      float u1 = __expf(lg[1]);
      float u2 = __expf(lg[2]);
      float rs = __builtin_amdgcn_rcpf((u0 + u1) + u2);
      float* op = out + (size_t)(T0 + g * 64 + tid) * 3;
      op[0] = u0 * rs;
      op[1] = u1 * rs;
      op[2] = u2 * rs;
    }
  }
}

extern "C" void kernel_launch(void* const* d_in, const int* in_sizes, int n_in,
                              void* d_out, int out_size, void* d_ws, size_t ws_size,
                              hipStream_t stream) {
  const float* tok = (const float*)d_in[0];
  const float* Wq  = (const float*)d_in[1];
  const float* Wk  = (const float*)d_in[2];
  const float* Wv  = (const float*)d_in[3];
  float* out = (float*)d_out;

  const int n_tokens = in_sizes[0] / 1024;   // 32768
  const int blocks   = n_tokens / TPB;       // 256

  hipLaunchKernelGGL(moa_mfma5, dim3(blocks), dim3(256), 0, stream,
                     tok, Wq, Wk, Wv, out);
}